// Round 14
// baseline (166.504 us; speedup 1.0000x reference)
//
#include <hip/hip_runtime.h>
#include <math.h>

#define NN   2048
#define KZ   20
#define IFZ  128
#define AHZ  4
#define AFZ  32
#define ROWS (NN*KZ)           // 40960
#define TWO_KZ (2*KZ)          // 40

typedef __attribute__((ext_vector_type(8))) short short8v;   // 8 bf16 = 4 VGPR
typedef __attribute__((ext_vector_type(4))) float f32x4;     // MFMA acc
typedef __attribute__((ext_vector_type(2))) float f32x2;

__device__ __forceinline__ float blo(unsigned int u) {      // low bf16 of packed pair
    union { unsigned int i; float f; } x; x.i = u << 16; return x.f;
}
__device__ __forceinline__ float bhi(unsigned int u) {      // high bf16 of packed pair
    union { unsigned int i; float f; } x; x.i = u & 0xffff0000u; return x.f;
}
__device__ __forceinline__ unsigned short f2b(float f) {
    union { float f; unsigned int i; } x; x.f = f;
    unsigned int r = x.i + 0x7fffu + ((x.i >> 16) & 1u);
    return (unsigned short)(r >> 16);
}
__device__ __forceinline__ unsigned pack2(float a, float b) {
    return (unsigned)f2b(a) | ((unsigned)f2b(b) << 16);
}
__device__ __forceinline__ float dot16(uint4 q, uint4 k) {  // 8 bf16-pair products
    return blo(q.x)*blo(k.x) + bhi(q.x)*bhi(k.x)
         + blo(q.y)*blo(k.y) + bhi(q.y)*bhi(k.y)
         + blo(q.z)*blo(k.z) + bhi(q.z)*bhi(k.z)
         + blo(q.w)*blo(k.w) + bhi(q.w)*bhi(k.w);
}

// ---------------------------------------------------------------------------
// setup: wtrans (blocks 0..319) | bproj f32 (320..479).
// ---------------------------------------------------------------------------
__global__ __launch_bounds__(256) void setup_kernel(
    const float* __restrict__ x,
    const float* __restrict__ Wq, const float* __restrict__ Wk,
    const float* __restrict__ Wv, const float* __restrict__ Wg,
    const float* __restrict__ Wback, const float* __restrict__ Wb,
    unsigned short* __restrict__ Wt, unsigned short* __restrict__ Wbt,
    float* __restrict__ bbuf)
{
    const int b   = blockIdx.x;
    const int tid = threadIdx.x;

    if (b < 320) {                        // ---- wtrans
        const int gid = b * 256 + tid;
        if (gid < 512 * 128) {
            const int n = gid >> 7, k = gid & 127;
            const float* W; int c;
            if      (n < 128) { W = Wq; c = n; }
            else if (n < 256) { W = Wk; c = n - 128; }
            else if (n < 384) { W = Wv; c = n - 256; }
            else              { W = Wg; c = n - 384; }
            Wt[gid] = f2b(W[k * 128 + c]);
        } else {
            const int g2 = gid - 512 * 128;
            const int n = g2 >> 7, k = g2 & 127;
            Wbt[g2] = f2b(Wback[k * 128 + n]);
        }
    } else {                              // ---- bproj (f32 x)
        const int row = (b - 320) * 256 + tid;
        const float4* xv = (const float4*)(x + (size_t)row * IFZ);
        const float4* wv = (const float4*)Wb;
        float4 acc = make_float4(0.f, 0.f, 0.f, 0.f);
        #pragma unroll
        for (int k4 = 0; k4 < 32; ++k4) {
            const float4 xc = xv[k4];
            float4 w;
            w = wv[k4*4+0]; acc.x += xc.x*w.x; acc.y += xc.x*w.y; acc.z += xc.x*w.z; acc.w += xc.x*w.w;
            w = wv[k4*4+1]; acc.x += xc.y*w.x; acc.y += xc.y*w.y; acc.z += xc.y*w.z; acc.w += xc.y*w.w;
            w = wv[k4*4+2]; acc.x += xc.z*w.x; acc.y += xc.z*w.y; acc.z += xc.z*w.z; acc.w += xc.z*w.w;
            w = wv[k4*4+3]; acc.x += xc.w*w.x; acc.y += xc.w*w.y; acc.z += xc.w*w.z; acc.w += xc.w*w.w;
        }
        ((float4*)bbuf)[row] = acc;
    }
}

// ---------------------------------------------------------------------------
// proj_gemm v3: reads f32 x directly, packs A-fragments to bf16 in regs.
// Swapped MFMA -> C^T frag -> packed uint2 stores.
// cc0->qb; cc1->kb+kf8; cc2->vf8 only; cc3->gb (gated).
// ---------------------------------------------------------------------------
__global__ __launch_bounds__(256) void proj_gemm(
    const float* __restrict__ x, const unsigned short* __restrict__ Wt,
    const float* __restrict__ bg,
    unsigned short* __restrict__ qb, unsigned short* __restrict__ kb,
    unsigned short* __restrict__ gb,
    unsigned char* __restrict__ kf8, unsigned char* __restrict__ vf8)
{
    const int row0 = blockIdx.x * 128;
    const int wid  = threadIdx.x >> 6;
    const int lane = threadIdx.x & 63;
    const int wm = wid >> 1, wn = wid & 1;
    const int l15 = lane & 15, lg = lane >> 4;

    short8v a[4][4];
    {
        const float* Af = x + ((size_t)(row0 + wm*64 + l15)) * IFZ + lg*8;
        #pragma unroll
        for (int ks = 0; ks < 4; ++ks)
            #pragma unroll
            for (int fm = 0; fm < 4; ++fm) {
                const float4 u0 = *(const float4*)(Af + (size_t)fm*16*IFZ + ks*32);
                const float4 u1 = *(const float4*)(Af + (size_t)fm*16*IFZ + ks*32 + 4);
                union { short8v s; uint4 u; } cv;
                cv.u.x = pack2(u0.x, u0.y);
                cv.u.y = pack2(u0.z, u0.w);
                cv.u.z = pack2(u1.x, u1.y);
                cv.u.w = pack2(u1.z, u1.w);
                a[ks][fm] = cv.s;
            }
    }

    #pragma unroll
    for (int cc = 0; cc < 4; ++cc) {
        const unsigned short* Bb = Wt + ((size_t)(cc*128 + wn*64 + l15)) * IFZ + lg*8;

        f32x4 acc[4][4];
        #pragma unroll
        for (int i = 0; i < 4; ++i)
            #pragma unroll
            for (int j = 0; j < 4; ++j) acc[i][j] = (f32x4){0.f,0.f,0.f,0.f};

        #pragma unroll
        for (int ks = 0; ks < 4; ++ks) {
            short8v b[4];
            #pragma unroll
            for (int f = 0; f < 4; ++f)
                b[f] = *((const short8v*)(Bb + (size_t)f*16*IFZ + ks*32));
            #pragma unroll
            for (int fm = 0; fm < 4; ++fm)
                #pragma unroll
                for (int fn = 0; fn < 4; ++fn)
                    acc[fm][fn] = __builtin_amdgcn_mfma_f32_16x16x32_bf16(
                        b[fn], a[ks][fm], acc[fm][fn], 0, 0, 0);   // SWAPPED
        }

        const bool gate = (cc == 3);
        unsigned short* ob = (cc == 0) ? qb : (cc == 1) ? kb : (cc == 3) ? gb : (unsigned short*)0;
        unsigned char*  f8 = (cc == 1) ? kf8 : (cc == 2) ? vf8 : (unsigned char*)0;

        #pragma unroll
        for (int fm = 0; fm < 4; ++fm) {
            const int row = row0 + wm*64 + fm*16 + l15;
            #pragma unroll
            for (int fn = 0; fn < 4; ++fn) {
                const int cbase = wn*64 + fn*16 + lg*4;
                float v0 = acc[fm][fn][0], v1 = acc[fm][fn][1];
                float v2 = acc[fm][fn][2], v3 = acc[fm][fn][3];
                if (gate) {
                    const float4 bg4 = *(const float4*)(bg + cbase);
                    v0 = 1.f/(1.f + __expf(-(v0 + bg4.x)));
                    v1 = 1.f/(1.f + __expf(-(v1 + bg4.y)));
                    v2 = 1.f/(1.f + __expf(-(v2 + bg4.z)));
                    v3 = 1.f/(1.f + __expf(-(v3 + bg4.w)));
                }
                if (ob) {
                    uint2 o;
                    o.x = pack2(v0, v1);
                    o.y = pack2(v2, v3);
                    *(uint2*)(ob + (size_t)row * IFZ + cbase) = o;
                }
                if (f8) {
                    int p = __builtin_amdgcn_cvt_pk_fp8_f32(v0, v1, 0, false);
                    p     = __builtin_amdgcn_cvt_pk_fp8_f32(v2, v3, p, true);
                    *(unsigned*)(f8 + (size_t)row*128 + cbase) = (unsigned)p;
                }
            }
        }
    }
}

// ---------------------------------------------------------------------------
// attn_back_ln v4: phase 3 remapped to 8-columns/thread (uint2 V loads,
// 4x fewer VMEM requests). Phases 1/2/4-7 identical to v3.
// ---------------------------------------------------------------------------
__global__ __launch_bounds__(256) void attn_back_ln(
    const unsigned short* __restrict__ qb, const unsigned short* __restrict__ kb,
    const unsigned short* __restrict__ gb,
    const float* __restrict__ bbuf, const int* __restrict__ edge,
    const unsigned char* __restrict__ kf8, const unsigned char* __restrict__ vf8,
    const float* __restrict__ x, const unsigned short* __restrict__ Wbt,
    const float* __restrict__ bback, const float* __restrict__ gamma,
    const float* __restrict__ beta, float* __restrict__ out)
{
    const int n   = blockIdx.x;
    const int tid = threadIdx.x;

    __shared__ unsigned smemA[KZ*80*2];  // qsu | ksu; ctxb aliases from phase 3
    __shared__ float    scys[3280];      // scores, then ys (aliased)
    __shared__ float    bs[KZ*AHZ];
    __shared__ float    st2[KZ][2];
    __shared__ int      es[KZ];

    unsigned* qsu  = smemA;              // [kk][a][20] packed bf16 pairs
    unsigned* ksu  = smemA + KZ*80;
    unsigned* ctxb = smemA;              // 32*68 uints; valid from phase 3 on

    const size_t base  = (size_t)n * (KZ*IFZ);
    const size_t base2 = base >> 1;              // uint index

    {
        const uint4* qsrc = (const uint4*)(qb + base);
        const uint4* ksrc = (const uint4*)(kb + base);
        for (int i = tid; i < KZ*16; i += 256) {
            const int r = i >> 4, u4 = i & 15;
            const int d = r*80 + (u4 >> 2)*20 + (u4 & 3)*4;
            *(uint4*)&qsu[d] = qsrc[i];
            *(uint4*)&ksu[d] = ksrc[i];
        }
    }
    if (tid < KZ)      es[tid] = edge[n*KZ + tid];
    if (tid < KZ*AHZ)  bs[tid] = bbuf[(size_t)n*(KZ*AHZ) + tid];
    __syncthreads();

    const float rscale = 0.17677669529663687f;  // 1/sqrt(32)

    // ---- Phase 1a: self scores, it-loop, transient regs (1600 items).
    for (int it = tid; it < KZ*KZ*AHZ; it += 256) {
        const int a  = it & 3;
        const int j  = (it >> 2) % KZ;
        const int kk = it / (KZ*AHZ);
        const unsigned* qrow = &qsu[kk*80 + a*20];
        const unsigned* krow = &ksu[j*80 + a*20];
        const uint4 q0 = *(const uint4*)&qrow[0];
        const uint4 q1 = *(const uint4*)&qrow[4];
        const uint4 q2 = *(const uint4*)&qrow[8];
        const uint4 q3 = *(const uint4*)&qrow[12];
        const uint4 k0 = *(const uint4*)&krow[0];
        const uint4 k1 = *(const uint4*)&krow[4];
        const uint4 k2 = *(const uint4*)&krow[8];
        const uint4 k3 = *(const uint4*)&krow[12];
        const float s = dot16(q0,k0) + dot16(q1,k1) + dot16(q2,k2) + dot16(q3,k3);
        scys[(kk*4 + a)*41 + j] = s*rscale + bs[j*AHZ + a];
    }

    // ---- Phase 1b: neighbor scores from kf8, it-loop (1600 items).
    for (int it = tid; it < KZ*KZ*AHZ; it += 256) {
        const int a  = it & 3;
        const int jj = (it >> 2) % KZ;
        const int kk = it / (KZ*AHZ);
        const int e  = es[kk];
        const unsigned* qrow = &qsu[kk*80 + a*20];
        const unsigned char* kp = kf8 + ((size_t)e*KZ + jj)*128 + a*32;
        const uint4 k1 = *(const uint4*)kp;
        const uint4 k2 = *(const uint4*)(kp + 16);
        unsigned ks_[8] = {k1.x, k1.y, k1.z, k1.w, k2.x, k2.y, k2.z, k2.w};
        float s = 0.f;
        #pragma unroll
        for (int u = 0; u < 8; ++u) {
            const f32x2 lo = __builtin_amdgcn_cvt_pk_f32_fp8(ks_[u], false);
            const f32x2 hi = __builtin_amdgcn_cvt_pk_f32_fp8(ks_[u], true);
            const unsigned q0 = qrow[2*u], q1 = qrow[2*u+1];
            s += blo(q0)*lo.x + bhi(q0)*lo.y + blo(q1)*hi.x + bhi(q1)*hi.y;
        }
        scys[(kk*4 + a)*41 + KZ + jj] = s*rscale + bbuf[((size_t)e*KZ + jj)*AHZ + a];
    }
    __syncthreads();

    // ---- Phase 2: softmax over 40 keys, one thread per (kk,a) row.
    if (tid < KZ*AHZ) {
        float* row = &scys[tid*41];
        float m = row[0];
        #pragma unroll
        for (int j = 1; j < TWO_KZ; ++j) m = fmaxf(m, row[j]);
        float ssum = 0.f;
        #pragma unroll
        for (int j = 0; j < TWO_KZ; ++j) { const float e = __expf(row[j]-m); row[j] = e; ssum += e; }
        const float inv = 1.f/ssum;
        #pragma unroll
        for (int j = 0; j < TWO_KZ; ++j) row[j] *= inv;
    }
    __syncthreads();     // qsu/ksu/bs now dead -> ctxb may overwrite

    // ---- Phase 3: ctx + gate -> ctxb. item = kk*16 + c8 (320 items, 8 cols).
    // uint2 (8B) V loads: 4x fewer VMEM requests than 2B column-pair loads.
    {
        for (int i = tid; i < 12*68; i += 256) ctxb[20*68 + i] = 0u;

        const unsigned* gbu = (const unsigned*)gb;
        for (int it = tid; it < KZ*16; it += 256) {
            const int kk = it >> 4;
            const int c8 = it & 15;          // cols [c8*8, c8*8+8)
            const int a  = c8 >> 2;
            const float* wrow = &scys[(kk*4 + a)*41];
            float acc[8];
            #pragma unroll
            for (int q = 0; q < 8; ++q) acc[q] = 0.f;

            const unsigned char* vself = vf8 + (size_t)n*(KZ*128) + c8*8;
            #pragma unroll
            for (int j = 0; j < KZ; ++j) {
                const uint2 v = *(const uint2*)(vself + j*128);
                const float w = wrow[j];
                f32x2 p;
                p = __builtin_amdgcn_cvt_pk_f32_fp8(v.x, false); acc[0]+=w*p.x; acc[1]+=w*p.y;
                p = __builtin_amdgcn_cvt_pk_f32_fp8(v.x, true);  acc[2]+=w*p.x; acc[3]+=w*p.y;
                p = __builtin_amdgcn_cvt_pk_f32_fp8(v.y, false); acc[4]+=w*p.x; acc[5]+=w*p.y;
                p = __builtin_amdgcn_cvt_pk_f32_fp8(v.y, true);  acc[6]+=w*p.x; acc[7]+=w*p.y;
            }
            const unsigned char* vnb = vf8 + (size_t)es[kk]*(KZ*128) + c8*8;
            #pragma unroll
            for (int j = 0; j < KZ; ++j) {
                const uint2 v = *(const uint2*)(vnb + j*128);
                const float w = wrow[KZ + j];
                f32x2 p;
                p = __builtin_amdgcn_cvt_pk_f32_fp8(v.x, false); acc[0]+=w*p.x; acc[1]+=w*p.y;
                p = __builtin_amdgcn_cvt_pk_f32_fp8(v.x, true);  acc[2]+=w*p.x; acc[3]+=w*p.y;
                p = __builtin_amdgcn_cvt_pk_f32_fp8(v.y, false); acc[4]+=w*p.x; acc[5]+=w*p.y;
                p = __builtin_amdgcn_cvt_pk_f32_fp8(v.y, true);  acc[6]+=w*p.x; acc[7]+=w*p.y;
            }
            #pragma unroll
            for (int q = 0; q < 4; ++q) {
                const unsigned gu = gbu[base2 + kk*64 + c8*4 + q];
                ctxb[kk*68 + c8*4 + q] = pack2(acc[2*q] * blo(gu), acc[2*q+1] * bhi(gu));
            }
        }
    }
    __syncthreads();     // ctxb ready; scys (scores) dead -> becomes ys

    // ---- Phase 4: back-GEMM compute (MFMA) + ys init (overlapped).
    const int wid  = tid >> 6;
    const int lane = tid & 63;
    const int l15  = lane & 15, lg = lane >> 4;
    const float SQ2 = 1.4142135623730951f;

    f32x4 bacc[2][2];
    #pragma unroll
    for (int i = 0; i < 2; ++i)
        #pragma unroll
        for (int j = 0; j < 2; ++j) bacc[i][j] = (f32x4){0.f,0.f,0.f,0.f};

    #pragma unroll
    for (int ks = 0; ks < 4; ++ks) {
        short8v bfr[2], afr[2];
        #pragma unroll
        for (int fn = 0; fn < 2; ++fn)
            bfr[fn] = *((const short8v*)(Wbt + (size_t)(wid*32 + fn*16 + l15)*IFZ + ks*32 + lg*8));
        #pragma unroll
        for (int fm = 0; fm < 2; ++fm)
            afr[fm] = *((const short8v*)&ctxb[(fm*16 + l15)*68 + ks*16 + lg*4]);
        #pragma unroll
        for (int fm = 0; fm < 2; ++fm)
            #pragma unroll
            for (int fn = 0; fn < 2; ++fn)
                bacc[fm][fn] = __builtin_amdgcn_mfma_f32_16x16x32_bf16(
                    bfr[fn], afr[fm], bacc[fm][fn], 0, 0, 0);   // SWAPPED
    }

    // ys init: ys[r][c] = sqrt2*x + bback (640 float4 items over 256 threads)
    for (int i = tid; i < 640; i += 256) {
        const int r = i >> 5, c4 = (i & 31) * 4;
        const float4 xv  = *(const float4*)(x + base + (size_t)r*IFZ + c4);
        const float4 bb4 = *(const float4*)(bback + c4);
        float* yp = &scys[r*132 + c4];
        yp[0] = SQ2*xv.x + bb4.x; yp[1] = SQ2*xv.y + bb4.y;
        yp[2] = SQ2*xv.z + bb4.z; yp[3] = SQ2*xv.w + bb4.w;
    }
    __syncthreads();

    // ---- Phase 5: add fragments into ys (unique (row,col) ownership).
    #pragma unroll
    for (int fm = 0; fm < 2; ++fm) {
        const int row = fm*16 + l15;
        if (row < KZ) {
            #pragma unroll
            for (int fn = 0; fn < 2; ++fn) {
                const int cb = wid*32 + fn*16 + lg*4;
                float* yp = &scys[row*132 + cb];
                yp[0] += bacc[fm][fn][0]; yp[1] += bacc[fm][fn][1];
                yp[2] += bacc[fm][fn][2]; yp[3] += bacc[fm][fn][3];
            }
        }
    }
    __syncthreads();

    // ---- Phase 6: LN stats, 8 threads per row (20 rows x 8 = 160).
    if (tid < 160) {
        const int row = tid >> 3, t = tid & 7;
        float s1 = 0.f, s2 = 0.f;
        #pragma unroll
        for (int i = 0; i < 16; ++i) {
            const float v = scys[row*132 + t*16 + i];
            s1 += v; s2 += v*v;
        }
        s1 += __shfl_xor(s1, 1); s2 += __shfl_xor(s2, 1);
        s1 += __shfl_xor(s1, 2); s2 += __shfl_xor(s2, 2);
        s1 += __shfl_xor(s1, 4); s2 += __shfl_xor(s2, 4);
        if (t == 0) {
            const float mean = s1 * (1.f/IFZ);
            const float var  = s2 * (1.f/IFZ) - mean*mean;
            st2[row][0] = mean;
            st2[row][1] = rsqrtf(var + 1e-5f);
        }
    }
    __syncthreads();

    // ---- Phase 7: normalize + write f32 out.
    for (int i = tid; i < 640; i += 256) {
        const int r = i >> 5, c4 = (i & 31) * 4;
        const float mean = st2[r][0], rstd = st2[r][1];
        const float4 g4 = *(const float4*)(gamma + c4);
        const float4 b4 = *(const float4*)(beta + c4);
        const float4 yv = *(const float4*)&scys[r*132 + c4];
        float4 o;
        o.x = g4.x*(yv.x - mean)*rstd + b4.x;
        o.y = g4.y*(yv.y - mean)*rstd + b4.y;
        o.z = g4.z*(yv.z - mean)*rstd + b4.z;
        o.w = g4.w*(yv.w - mean)*rstd + b4.w;
        *(float4*)(out + base + (size_t)r*IFZ + c4) = o;
    }
}

// ---------------------------------------------------------------------------
extern "C" void kernel_launch(void* const* d_in, const int* in_sizes, int n_in,
                              void* d_out, int out_size, void* d_ws, size_t ws_size,
                              hipStream_t stream) {
    const float* x     = (const float*)d_in[0];
    const int*   edge  = (const int*)  d_in[1];
    const float* Wq    = (const float*)d_in[2];
    const float* Wk    = (const float*)d_in[3];
    const float* Wv    = (const float*)d_in[4];
    const float* Wb    = (const float*)d_in[5];
    const float* Wg    = (const float*)d_in[6];
    const float* bg    = (const float*)d_in[7];
    const float* Wback = (const float*)d_in[8];
    const float* bback = (const float*)d_in[9];
    const float* gamma = (const float*)d_in[10];
    const float* beta  = (const float*)d_in[11];
    float* out = (float*)d_out;

    const size_t RE = (size_t)ROWS * IFZ;   // 5,242,880 elements
    unsigned short* qb  = (unsigned short*)d_ws;
    unsigned short* kb  = qb + RE;
    unsigned short* gb  = kb + RE;
    unsigned short* Wt  = gb + RE;          // 512*128
    unsigned short* Wbt = Wt + 512*128;     // 128*128
    float*          bbuf= (float*)(Wbt + 128*128);   // ROWS*4 f32
    unsigned char*  kf8 = (unsigned char*)(bbuf + (size_t)ROWS*4);  // ROWS*128 B
    unsigned char*  vf8 = kf8 + RE;                                  // ROWS*128 B
    // total ws use ~43 MB

    setup_kernel<<<480, 256, 0, stream>>>(x, Wq, Wk, Wv, Wg, Wback, Wb,
                                          Wt, Wbt, bbuf);
    proj_gemm  <<<ROWS/128, 256, 0, stream>>>(x, Wt, bg, qb, kb, gb, kf8, vf8);
    attn_back_ln<<<NN, 256, 0, stream>>>(qb, kb, gb, bbuf, edge, kf8, vf8,
                                         x, Wbt, bback, gamma, beta, out);
}

// Round 15
// 110.556 us; speedup vs baseline: 1.5061x; 1.5061x over previous
//
#include <hip/hip_runtime.h>
#include <math.h>

#define NN   2048
#define KZ   20
#define IFZ  128
#define AHZ  4
#define AFZ  32
#define ROWS (NN*KZ)           // 40960
#define TWO_KZ (2*KZ)          // 40

typedef __attribute__((ext_vector_type(8))) short short8v;   // 8 bf16 = 4 VGPR
typedef __attribute__((ext_vector_type(4))) float f32x4;     // MFMA acc
typedef __attribute__((ext_vector_type(2))) float f32x2;

__device__ __forceinline__ float blo(unsigned int u) {      // low bf16 of packed pair
    union { unsigned int i; float f; } x; x.i = u << 16; return x.f;
}
__device__ __forceinline__ float bhi(unsigned int u) {      // high bf16 of packed pair
    union { unsigned int i; float f; } x; x.i = u & 0xffff0000u; return x.f;
}
__device__ __forceinline__ unsigned short f2b(float f) {
    union { float f; unsigned int i; } x; x.f = f;
    unsigned int r = x.i + 0x7fffu + ((x.i >> 16) & 1u);
    return (unsigned short)(r >> 16);
}
__device__ __forceinline__ unsigned pack2(float a, float b) {
    return (unsigned)f2b(a) | ((unsigned)f2b(b) << 16);
}
__device__ __forceinline__ float dot16(uint4 q, uint4 k) {  // 8 bf16-pair products
    return blo(q.x)*blo(k.x) + bhi(q.x)*bhi(k.x)
         + blo(q.y)*blo(k.y) + bhi(q.y)*bhi(k.y)
         + blo(q.z)*blo(k.z) + bhi(q.z)*bhi(k.z)
         + blo(q.w)*blo(k.w) + bhi(q.w)*bhi(k.w);
}

// ---------------------------------------------------------------------------
// setup: wtrans (blocks 0..319) | bproj f32 (320..479).
// ---------------------------------------------------------------------------
__global__ __launch_bounds__(256) void setup_kernel(
    const float* __restrict__ x,
    const float* __restrict__ Wq, const float* __restrict__ Wk,
    const float* __restrict__ Wv, const float* __restrict__ Wg,
    const float* __restrict__ Wback, const float* __restrict__ Wb,
    unsigned short* __restrict__ Wt, unsigned short* __restrict__ Wbt,
    float* __restrict__ bbuf)
{
    const int b   = blockIdx.x;
    const int tid = threadIdx.x;

    if (b < 320) {                        // ---- wtrans
        const int gid = b * 256 + tid;
        if (gid < 512 * 128) {
            const int n = gid >> 7, k = gid & 127;
            const float* W; int c;
            if      (n < 128) { W = Wq; c = n; }
            else if (n < 256) { W = Wk; c = n - 128; }
            else if (n < 384) { W = Wv; c = n - 256; }
            else              { W = Wg; c = n - 384; }
            Wt[gid] = f2b(W[k * 128 + c]);
        } else {
            const int g2 = gid - 512 * 128;
            const int n = g2 >> 7, k = g2 & 127;
            Wbt[g2] = f2b(Wback[k * 128 + n]);
        }
    } else {                              // ---- bproj (f32 x)
        const int row = (b - 320) * 256 + tid;
        const float4* xv = (const float4*)(x + (size_t)row * IFZ);
        const float4* wv = (const float4*)Wb;
        float4 acc = make_float4(0.f, 0.f, 0.f, 0.f);
        #pragma unroll
        for (int k4 = 0; k4 < 32; ++k4) {
            const float4 xc = xv[k4];
            float4 w;
            w = wv[k4*4+0]; acc.x += xc.x*w.x; acc.y += xc.x*w.y; acc.z += xc.x*w.z; acc.w += xc.x*w.w;
            w = wv[k4*4+1]; acc.x += xc.y*w.x; acc.y += xc.y*w.y; acc.z += xc.y*w.z; acc.w += xc.y*w.w;
            w = wv[k4*4+2]; acc.x += xc.z*w.x; acc.y += xc.z*w.y; acc.z += xc.z*w.z; acc.w += xc.z*w.w;
            w = wv[k4*4+3]; acc.x += xc.w*w.x; acc.y += xc.w*w.y; acc.z += xc.w*w.z; acc.w += xc.w*w.w;
        }
        ((float4*)bbuf)[row] = acc;
    }
}

// ---------------------------------------------------------------------------
// proj_gemm v3: reads f32 x directly, packs A-fragments to bf16 in regs.
// Swapped MFMA -> C^T frag -> packed uint2 stores.
// cc0->qb; cc1->kb+kf8; cc2->vf8 only; cc3->gb (gated).
// ---------------------------------------------------------------------------
__global__ __launch_bounds__(256) void proj_gemm(
    const float* __restrict__ x, const unsigned short* __restrict__ Wt,
    const float* __restrict__ bg,
    unsigned short* __restrict__ qb, unsigned short* __restrict__ kb,
    unsigned short* __restrict__ gb,
    unsigned char* __restrict__ kf8, unsigned char* __restrict__ vf8)
{
    const int row0 = blockIdx.x * 128;
    const int wid  = threadIdx.x >> 6;
    const int lane = threadIdx.x & 63;
    const int wm = wid >> 1, wn = wid & 1;
    const int l15 = lane & 15, lg = lane >> 4;

    short8v a[4][4];
    {
        const float* Af = x + ((size_t)(row0 + wm*64 + l15)) * IFZ + lg*8;
        #pragma unroll
        for (int ks = 0; ks < 4; ++ks)
            #pragma unroll
            for (int fm = 0; fm < 4; ++fm) {
                const float4 u0 = *(const float4*)(Af + (size_t)fm*16*IFZ + ks*32);
                const float4 u1 = *(const float4*)(Af + (size_t)fm*16*IFZ + ks*32 + 4);
                union { short8v s; uint4 u; } cv;
                cv.u.x = pack2(u0.x, u0.y);
                cv.u.y = pack2(u0.z, u0.w);
                cv.u.z = pack2(u1.x, u1.y);
                cv.u.w = pack2(u1.z, u1.w);
                a[ks][fm] = cv.s;
            }
    }

    #pragma unroll
    for (int cc = 0; cc < 4; ++cc) {
        const unsigned short* Bb = Wt + ((size_t)(cc*128 + wn*64 + l15)) * IFZ + lg*8;

        f32x4 acc[4][4];
        #pragma unroll
        for (int i = 0; i < 4; ++i)
            #pragma unroll
            for (int j = 0; j < 4; ++j) acc[i][j] = (f32x4){0.f,0.f,0.f,0.f};

        #pragma unroll
        for (int ks = 0; ks < 4; ++ks) {
            short8v b[4];
            #pragma unroll
            for (int f = 0; f < 4; ++f)
                b[f] = *((const short8v*)(Bb + (size_t)f*16*IFZ + ks*32));
            #pragma unroll
            for (int fm = 0; fm < 4; ++fm)
                #pragma unroll
                for (int fn = 0; fn < 4; ++fn)
                    acc[fm][fn] = __builtin_amdgcn_mfma_f32_16x16x32_bf16(
                        b[fn], a[ks][fm], acc[fm][fn], 0, 0, 0);   // SWAPPED
        }

        const bool gate = (cc == 3);
        unsigned short* ob = (cc == 0) ? qb : (cc == 1) ? kb : (cc == 3) ? gb : (unsigned short*)0;
        unsigned char*  f8 = (cc == 1) ? kf8 : (cc == 2) ? vf8 : (unsigned char*)0;

        #pragma unroll
        for (int fm = 0; fm < 4; ++fm) {
            const int row = row0 + wm*64 + fm*16 + l15;
            #pragma unroll
            for (int fn = 0; fn < 4; ++fn) {
                const int cbase = wn*64 + fn*16 + lg*4;
                float v0 = acc[fm][fn][0], v1 = acc[fm][fn][1];
                float v2 = acc[fm][fn][2], v3 = acc[fm][fn][3];
                if (gate) {
                    const float4 bg4 = *(const float4*)(bg + cbase);
                    v0 = 1.f/(1.f + __expf(-(v0 + bg4.x)));
                    v1 = 1.f/(1.f + __expf(-(v1 + bg4.y)));
                    v2 = 1.f/(1.f + __expf(-(v2 + bg4.z)));
                    v3 = 1.f/(1.f + __expf(-(v3 + bg4.w)));
                }
                if (ob) {
                    uint2 o;
                    o.x = pack2(v0, v1);
                    o.y = pack2(v2, v3);
                    *(uint2*)(ob + (size_t)row * IFZ + cbase) = o;
                }
                if (f8) {
                    int p = __builtin_amdgcn_cvt_pk_fp8_f32(v0, v1, 0, false);
                    p     = __builtin_amdgcn_cvt_pk_fp8_f32(v2, v3, p, true);
                    *(unsigned*)(f8 + (size_t)row*128 + cbase) = (unsigned)p;
                }
            }
        }
    }
}

// ---------------------------------------------------------------------------
// attn_back_ln v5: R13 structure; phase 3 thread owns 4 columns (uint 4B V
// loads, 2x fewer VMEM requests than R13) with scalar accumulators and
// `#pragma unroll 5` caps so the compiler cannot hoist all 20 loads.
// ---------------------------------------------------------------------------
__global__ __launch_bounds__(256) void attn_back_ln(
    const unsigned short* __restrict__ qb, const unsigned short* __restrict__ kb,
    const unsigned short* __restrict__ gb,
    const float* __restrict__ bbuf, const int* __restrict__ edge,
    const unsigned char* __restrict__ kf8, const unsigned char* __restrict__ vf8,
    const float* __restrict__ x, const unsigned short* __restrict__ Wbt,
    const float* __restrict__ bback, const float* __restrict__ gamma,
    const float* __restrict__ beta, float* __restrict__ out)
{
    const int n   = blockIdx.x;
    const int tid = threadIdx.x;

    __shared__ unsigned smemA[KZ*80*2];  // qsu | ksu; ctxb aliases from phase 3
    __shared__ float    scys[3280];      // scores, then ys (aliased)
    __shared__ float    bs[KZ*AHZ];
    __shared__ float    st2[KZ][2];
    __shared__ int      es[KZ];

    unsigned* qsu  = smemA;              // [kk][a][20] packed bf16 pairs
    unsigned* ksu  = smemA + KZ*80;
    unsigned* ctxb = smemA;              // 32*68 uints; valid from phase 3 on

    const size_t base  = (size_t)n * (KZ*IFZ);
    const size_t base2 = base >> 1;              // uint index

    {
        const uint4* qsrc = (const uint4*)(qb + base);
        const uint4* ksrc = (const uint4*)(kb + base);
        for (int i = tid; i < KZ*16; i += 256) {
            const int r = i >> 4, u4 = i & 15;
            const int d = r*80 + (u4 >> 2)*20 + (u4 & 3)*4;
            *(uint4*)&qsu[d] = qsrc[i];
            *(uint4*)&ksu[d] = ksrc[i];
        }
    }
    if (tid < KZ)      es[tid] = edge[n*KZ + tid];
    if (tid < KZ*AHZ)  bs[tid] = bbuf[(size_t)n*(KZ*AHZ) + tid];
    __syncthreads();

    const float rscale = 0.17677669529663687f;  // 1/sqrt(32)

    // ---- Phase 1a: self scores, it-loop, transient regs (1600 items).
    for (int it = tid; it < KZ*KZ*AHZ; it += 256) {
        const int a  = it & 3;
        const int j  = (it >> 2) % KZ;
        const int kk = it / (KZ*AHZ);
        const unsigned* qrow = &qsu[kk*80 + a*20];
        const unsigned* krow = &ksu[j*80 + a*20];
        const uint4 q0 = *(const uint4*)&qrow[0];
        const uint4 q1 = *(const uint4*)&qrow[4];
        const uint4 q2 = *(const uint4*)&qrow[8];
        const uint4 q3 = *(const uint4*)&qrow[12];
        const uint4 k0 = *(const uint4*)&krow[0];
        const uint4 k1 = *(const uint4*)&krow[4];
        const uint4 k2 = *(const uint4*)&krow[8];
        const uint4 k3 = *(const uint4*)&krow[12];
        const float s = dot16(q0,k0) + dot16(q1,k1) + dot16(q2,k2) + dot16(q3,k3);
        scys[(kk*4 + a)*41 + j] = s*rscale + bs[j*AHZ + a];
    }

    // ---- Phase 1b: neighbor scores from kf8, it-loop (1600 items).
    for (int it = tid; it < KZ*KZ*AHZ; it += 256) {
        const int a  = it & 3;
        const int jj = (it >> 2) % KZ;
        const int kk = it / (KZ*AHZ);
        const int e  = es[kk];
        const unsigned* qrow = &qsu[kk*80 + a*20];
        const unsigned char* kp = kf8 + ((size_t)e*KZ + jj)*128 + a*32;
        const uint4 k1 = *(const uint4*)kp;
        const uint4 k2 = *(const uint4*)(kp + 16);
        unsigned ks_[8] = {k1.x, k1.y, k1.z, k1.w, k2.x, k2.y, k2.z, k2.w};
        float s = 0.f;
        #pragma unroll
        for (int u = 0; u < 8; ++u) {
            const f32x2 lo = __builtin_amdgcn_cvt_pk_f32_fp8(ks_[u], false);
            const f32x2 hi = __builtin_amdgcn_cvt_pk_f32_fp8(ks_[u], true);
            const unsigned q0 = qrow[2*u], q1 = qrow[2*u+1];
            s += blo(q0)*lo.x + bhi(q0)*lo.y + blo(q1)*hi.x + bhi(q1)*hi.y;
        }
        scys[(kk*4 + a)*41 + KZ + jj] = s*rscale + bbuf[((size_t)e*KZ + jj)*AHZ + a];
    }
    __syncthreads();

    // ---- Phase 2: softmax over 40 keys, one thread per (kk,a) row.
    if (tid < KZ*AHZ) {
        float* row = &scys[tid*41];
        float m = row[0];
        #pragma unroll
        for (int j = 1; j < TWO_KZ; ++j) m = fmaxf(m, row[j]);
        float ssum = 0.f;
        #pragma unroll
        for (int j = 0; j < TWO_KZ; ++j) { const float e = __expf(row[j]-m); row[j] = e; ssum += e; }
        const float inv = 1.f/ssum;
        #pragma unroll
        for (int j = 0; j < TWO_KZ; ++j) row[j] *= inv;
    }
    __syncthreads();     // qsu/ksu/bs now dead -> ctxb may overwrite

    // ---- Phase 3: ctx + gate -> ctxb. item = kk*32 + c4 (640 items, 4 cols).
    // uint (4B) V loads: 2x fewer VMEM requests than R13; unroll capped at 5
    // so at most ~5 loads are in flight (no register blowup).
    {
        for (int i = tid; i < 12*68; i += 256) ctxb[20*68 + i] = 0u;

        const unsigned* gbu = (const unsigned*)gb;
        for (int it = tid; it < KZ*32; it += 256) {
            const int kk = it >> 5;
            const int c4 = it & 31;          // cols [c4*4, c4*4+4)
            const int a  = c4 >> 3;
            const float* wrow = &scys[(kk*4 + a)*41];
            float acc0 = 0.f, acc1 = 0.f, acc2 = 0.f, acc3 = 0.f;

            const unsigned char* vself = vf8 + (size_t)n*(KZ*128) + c4*4;
            #pragma unroll 5
            for (int j = 0; j < KZ; ++j) {
                const unsigned v = *(const unsigned*)(vself + j*128);
                const float w = wrow[j];
                const f32x2 p0 = __builtin_amdgcn_cvt_pk_f32_fp8(v, false);
                const f32x2 p1 = __builtin_amdgcn_cvt_pk_f32_fp8(v, true);
                acc0 += w*p0.x; acc1 += w*p0.y; acc2 += w*p1.x; acc3 += w*p1.y;
            }
            const unsigned char* vnb = vf8 + (size_t)es[kk]*(KZ*128) + c4*4;
            #pragma unroll 5
            for (int j = 0; j < KZ; ++j) {
                const unsigned v = *(const unsigned*)(vnb + j*128);
                const float w = wrow[KZ + j];
                const f32x2 p0 = __builtin_amdgcn_cvt_pk_f32_fp8(v, false);
                const f32x2 p1 = __builtin_amdgcn_cvt_pk_f32_fp8(v, true);
                acc0 += w*p0.x; acc1 += w*p0.y; acc2 += w*p1.x; acc3 += w*p1.y;
            }
            const unsigned gu0 = gbu[base2 + kk*64 + c4*2];
            const unsigned gu1 = gbu[base2 + kk*64 + c4*2 + 1];
            ctxb[kk*68 + c4*2]     = pack2(acc0 * blo(gu0), acc1 * bhi(gu0));
            ctxb[kk*68 + c4*2 + 1] = pack2(acc2 * blo(gu1), acc3 * bhi(gu1));
        }
    }
    __syncthreads();     // ctxb ready; scys (scores) dead -> becomes ys

    // ---- Phase 4: back-GEMM compute (MFMA) + ys init (overlapped).
    const int wid  = tid >> 6;
    const int lane = tid & 63;
    const int l15  = lane & 15, lg = lane >> 4;
    const float SQ2 = 1.4142135623730951f;

    f32x4 bacc[2][2];
    #pragma unroll
    for (int i = 0; i < 2; ++i)
        #pragma unroll
        for (int j = 0; j < 2; ++j) bacc[i][j] = (f32x4){0.f,0.f,0.f,0.f};

    #pragma unroll
    for (int ks = 0; ks < 4; ++ks) {
        short8v bfr[2], afr[2];
        #pragma unroll
        for (int fn = 0; fn < 2; ++fn)
            bfr[fn] = *((const short8v*)(Wbt + (size_t)(wid*32 + fn*16 + l15)*IFZ + ks*32 + lg*8));
        #pragma unroll
        for (int fm = 0; fm < 2; ++fm)
            afr[fm] = *((const short8v*)&ctxb[(fm*16 + l15)*68 + ks*16 + lg*4]);
        #pragma unroll
        for (int fm = 0; fm < 2; ++fm)
            #pragma unroll
            for (int fn = 0; fn < 2; ++fn)
                bacc[fm][fn] = __builtin_amdgcn_mfma_f32_16x16x32_bf16(
                    bfr[fn], afr[fm], bacc[fm][fn], 0, 0, 0);   // SWAPPED
    }

    // ys init: ys[r][c] = sqrt2*x + bback (640 float4 items over 256 threads)
    for (int i = tid; i < 640; i += 256) {
        const int r = i >> 5, c4 = (i & 31) * 4;
        const float4 xv  = *(const float4*)(x + base + (size_t)r*IFZ + c4);
        const float4 bb4 = *(const float4*)(bback + c4);
        float* yp = &scys[r*132 + c4];
        yp[0] = SQ2*xv.x + bb4.x; yp[1] = SQ2*xv.y + bb4.y;
        yp[2] = SQ2*xv.z + bb4.z; yp[3] = SQ2*xv.w + bb4.w;
    }
    __syncthreads();

    // ---- Phase 5: add fragments into ys (unique (row,col) ownership).
    #pragma unroll
    for (int fm = 0; fm < 2; ++fm) {
        const int row = fm*16 + l15;
        if (row < KZ) {
            #pragma unroll
            for (int fn = 0; fn < 2; ++fn) {
                const int cb = wid*32 + fn*16 + lg*4;
                float* yp = &scys[row*132 + cb];
                yp[0] += bacc[fm][fn][0]; yp[1] += bacc[fm][fn][1];
                yp[2] += bacc[fm][fn][2]; yp[3] += bacc[fm][fn][3];
            }
        }
    }
    __syncthreads();

    // ---- Phase 6: LN stats, 8 threads per row (20 rows x 8 = 160).
    if (tid < 160) {
        const int row = tid >> 3, t = tid & 7;
        float s1 = 0.f, s2 = 0.f;
        #pragma unroll
        for (int i = 0; i < 16; ++i) {
            const float v = scys[row*132 + t*16 + i];
            s1 += v; s2 += v*v;
        }
        s1 += __shfl_xor(s1, 1); s2 += __shfl_xor(s2, 1);
        s1 += __shfl_xor(s1, 2); s2 += __shfl_xor(s2, 2);
        s1 += __shfl_xor(s1, 4); s2 += __shfl_xor(s2, 4);
        if (t == 0) {
            const float mean = s1 * (1.f/IFZ);
            const float var  = s2 * (1.f/IFZ) - mean*mean;
            st2[row][0] = mean;
            st2[row][1] = rsqrtf(var + 1e-5f);
        }
    }
    __syncthreads();

    // ---- Phase 7: normalize + write f32 out.
    for (int i = tid; i < 640; i += 256) {
        const int r = i >> 5, c4 = (i & 31) * 4;
        const float mean = st2[r][0], rstd = st2[r][1];
        const float4 g4 = *(const float4*)(gamma + c4);
        const float4 b4 = *(const float4*)(beta + c4);
        const float4 yv = *(const float4*)&scys[r*132 + c4];
        float4 o;
        o.x = g4.x*(yv.x - mean)*rstd + b4.x;
        o.y = g4.y*(yv.y - mean)*rstd + b4.y;
        o.z = g4.z*(yv.z - mean)*rstd + b4.z;
        o.w = g4.w*(yv.w - mean)*rstd + b4.w;
        *(float4*)(out + base + (size_t)r*IFZ + c4) = o;
    }
}

// ---------------------------------------------------------------------------
extern "C" void kernel_launch(void* const* d_in, const int* in_sizes, int n_in,
                              void* d_out, int out_size, void* d_ws, size_t ws_size,
                              hipStream_t stream) {
    const float* x     = (const float*)d_in[0];
    const int*   edge  = (const int*)  d_in[1];
    const float* Wq    = (const float*)d_in[2];
    const float* Wk    = (const float*)d_in[3];
    const float* Wv    = (const float*)d_in[4];
    const float* Wb    = (const float*)d_in[5];
    const float* Wg    = (const float*)d_in[6];
    const float* bg    = (const float*)d_in[7];
    const float* Wback = (const float*)d_in[8];
    const float* bback = (const float*)d_in[9];
    const float* gamma = (const float*)d_in[10];
    const float* beta  = (const float*)d_in[11];
    float* out = (float*)d_out;

    const size_t RE = (size_t)ROWS * IFZ;   // 5,242,880 elements
    unsigned short* qb  = (unsigned short*)d_ws;
    unsigned short* kb  = qb + RE;
    unsigned short* gb  = kb + RE;
    unsigned short* Wt  = gb + RE;          // 512*128
    unsigned short* Wbt = Wt + 512*128;     // 128*128
    float*          bbuf= (float*)(Wbt + 128*128);   // ROWS*4 f32
    unsigned char*  kf8 = (unsigned char*)(bbuf + (size_t)ROWS*4);  // ROWS*128 B
    unsigned char*  vf8 = kf8 + RE;                                  // ROWS*128 B
    // total ws use ~43 MB

    setup_kernel<<<480, 256, 0, stream>>>(x, Wq, Wk, Wv, Wg, Wback, Wb,
                                          Wt, Wbt, bbuf);
    proj_gemm  <<<ROWS/128, 256, 0, stream>>>(x, Wt, bg, qb, kb, gb, kf8, vf8);
    attn_back_ln<<<NN, 256, 0, stream>>>(qb, kb, gb, bbuf, edge, kf8, vf8,
                                         x, Wbt, bback, gamma, beta, out);
}

// Round 16
// 95.325 us; speedup vs baseline: 1.7467x; 1.1598x over previous
//
#include <hip/hip_runtime.h>
#include <math.h>

#define NN   2048
#define KZ   20
#define IFZ  128
#define AHZ  4
#define AFZ  32
#define ROWS (NN*KZ)           // 40960
#define TWO_KZ (2*KZ)          // 40

typedef __attribute__((ext_vector_type(8))) short short8v;   // 8 bf16 = 4 VGPR
typedef __attribute__((ext_vector_type(4))) float f32x4;     // MFMA acc
typedef __attribute__((ext_vector_type(2))) float f32x2;

__device__ __forceinline__ float blo(unsigned int u) {      // low bf16 of packed pair
    union { unsigned int i; float f; } x; x.i = u << 16; return x.f;
}
__device__ __forceinline__ float bhi(unsigned int u) {      // high bf16 of packed pair
    union { unsigned int i; float f; } x; x.i = u & 0xffff0000u; return x.f;
}
__device__ __forceinline__ unsigned short f2b(float f) {
    union { float f; unsigned int i; } x; x.f = f;
    unsigned int r = x.i + 0x7fffu + ((x.i >> 16) & 1u);
    return (unsigned short)(r >> 16);
}
__device__ __forceinline__ unsigned pack2(float a, float b) {
    return (unsigned)f2b(a) | ((unsigned)f2b(b) << 16);
}
// fp8 dot: 16 fp8 elems (uint4) from q and k
__device__ __forceinline__ float dotf8_16(uint4 q, uint4 k) {
    float s = 0.f;
    f32x2 ql, qh, kl, kh;
    ql = __builtin_amdgcn_cvt_pk_f32_fp8(q.x, false); qh = __builtin_amdgcn_cvt_pk_f32_fp8(q.x, true);
    kl = __builtin_amdgcn_cvt_pk_f32_fp8(k.x, false); kh = __builtin_amdgcn_cvt_pk_f32_fp8(k.x, true);
    s += ql.x*kl.x + ql.y*kl.y + qh.x*kh.x + qh.y*kh.y;
    ql = __builtin_amdgcn_cvt_pk_f32_fp8(q.y, false); qh = __builtin_amdgcn_cvt_pk_f32_fp8(q.y, true);
    kl = __builtin_amdgcn_cvt_pk_f32_fp8(k.y, false); kh = __builtin_amdgcn_cvt_pk_f32_fp8(k.y, true);
    s += ql.x*kl.x + ql.y*kl.y + qh.x*kh.x + qh.y*kh.y;
    ql = __builtin_amdgcn_cvt_pk_f32_fp8(q.z, false); qh = __builtin_amdgcn_cvt_pk_f32_fp8(q.z, true);
    kl = __builtin_amdgcn_cvt_pk_f32_fp8(k.z, false); kh = __builtin_amdgcn_cvt_pk_f32_fp8(k.z, true);
    s += ql.x*kl.x + ql.y*kl.y + qh.x*kh.x + qh.y*kh.y;
    ql = __builtin_amdgcn_cvt_pk_f32_fp8(q.w, false); qh = __builtin_amdgcn_cvt_pk_f32_fp8(q.w, true);
    kl = __builtin_amdgcn_cvt_pk_f32_fp8(k.w, false); kh = __builtin_amdgcn_cvt_pk_f32_fp8(k.w, true);
    s += ql.x*kl.x + ql.y*kl.y + qh.x*kh.x + qh.y*kh.y;
    return s;
}

// ---------------------------------------------------------------------------
// setup: wtrans (blocks 0..319) | bproj f32 (320..479).
// ---------------------------------------------------------------------------
__global__ __launch_bounds__(256) void setup_kernel(
    const float* __restrict__ x,
    const float* __restrict__ Wq, const float* __restrict__ Wk,
    const float* __restrict__ Wv, const float* __restrict__ Wg,
    const float* __restrict__ Wback, const float* __restrict__ Wb,
    unsigned short* __restrict__ Wt, unsigned short* __restrict__ Wbt,
    float* __restrict__ bbuf)
{
    const int b   = blockIdx.x;
    const int tid = threadIdx.x;

    if (b < 320) {                        // ---- wtrans
        const int gid = b * 256 + tid;
        if (gid < 512 * 128) {
            const int n = gid >> 7, k = gid & 127;
            const float* W; int c;
            if      (n < 128) { W = Wq; c = n; }
            else if (n < 256) { W = Wk; c = n - 128; }
            else if (n < 384) { W = Wv; c = n - 256; }
            else              { W = Wg; c = n - 384; }
            Wt[gid] = f2b(W[k * 128 + c]);
        } else {
            const int g2 = gid - 512 * 128;
            const int n = g2 >> 7, k = g2 & 127;
            Wbt[g2] = f2b(Wback[k * 128 + n]);
        }
    } else {                              // ---- bproj (f32 x)
        const int row = (b - 320) * 256 + tid;
        const float4* xv = (const float4*)(x + (size_t)row * IFZ);
        const float4* wv = (const float4*)Wb;
        float4 acc = make_float4(0.f, 0.f, 0.f, 0.f);
        #pragma unroll
        for (int k4 = 0; k4 < 32; ++k4) {
            const float4 xc = xv[k4];
            float4 w;
            w = wv[k4*4+0]; acc.x += xc.x*w.x; acc.y += xc.x*w.y; acc.z += xc.x*w.z; acc.w += xc.x*w.w;
            w = wv[k4*4+1]; acc.x += xc.y*w.x; acc.y += xc.y*w.y; acc.z += xc.y*w.z; acc.w += xc.y*w.w;
            w = wv[k4*4+2]; acc.x += xc.z*w.x; acc.y += xc.z*w.y; acc.z += xc.z*w.z; acc.w += xc.z*w.w;
            w = wv[k4*4+3]; acc.x += xc.w*w.x; acc.y += xc.w*w.y; acc.z += xc.w*w.z; acc.w += xc.w*w.w;
        }
        ((float4*)bbuf)[row] = acc;
    }
}

// ---------------------------------------------------------------------------
// proj_gemm v4: f32 x in regs -> bf16 A-frags; swapped MFMA -> C^T frags.
// cc0 -> qf8 only; cc1 -> kf8 only; cc2 -> vf8 only; cc3 -> gb bf16 (gated).
// ---------------------------------------------------------------------------
__global__ __launch_bounds__(256) void proj_gemm(
    const float* __restrict__ x, const unsigned short* __restrict__ Wt,
    const float* __restrict__ bg,
    unsigned short* __restrict__ gb,
    unsigned char* __restrict__ qf8, unsigned char* __restrict__ kf8,
    unsigned char* __restrict__ vf8)
{
    const int row0 = blockIdx.x * 128;
    const int wid  = threadIdx.x >> 6;
    const int lane = threadIdx.x & 63;
    const int wm = wid >> 1, wn = wid & 1;
    const int l15 = lane & 15, lg = lane >> 4;

    short8v a[4][4];
    {
        const float* Af = x + ((size_t)(row0 + wm*64 + l15)) * IFZ + lg*8;
        #pragma unroll
        for (int ks = 0; ks < 4; ++ks)
            #pragma unroll
            for (int fm = 0; fm < 4; ++fm) {
                const float4 u0 = *(const float4*)(Af + (size_t)fm*16*IFZ + ks*32);
                const float4 u1 = *(const float4*)(Af + (size_t)fm*16*IFZ + ks*32 + 4);
                union { short8v s; uint4 u; } cv;
                cv.u.x = pack2(u0.x, u0.y);
                cv.u.y = pack2(u0.z, u0.w);
                cv.u.z = pack2(u1.x, u1.y);
                cv.u.w = pack2(u1.z, u1.w);
                a[ks][fm] = cv.s;
            }
    }

    #pragma unroll
    for (int cc = 0; cc < 4; ++cc) {
        const unsigned short* Bb = Wt + ((size_t)(cc*128 + wn*64 + l15)) * IFZ + lg*8;

        f32x4 acc[4][4];
        #pragma unroll
        for (int i = 0; i < 4; ++i)
            #pragma unroll
            for (int j = 0; j < 4; ++j) acc[i][j] = (f32x4){0.f,0.f,0.f,0.f};

        #pragma unroll
        for (int ks = 0; ks < 4; ++ks) {
            short8v b[4];
            #pragma unroll
            for (int f = 0; f < 4; ++f)
                b[f] = *((const short8v*)(Bb + (size_t)f*16*IFZ + ks*32));
            #pragma unroll
            for (int fm = 0; fm < 4; ++fm)
                #pragma unroll
                for (int fn = 0; fn < 4; ++fn)
                    acc[fm][fn] = __builtin_amdgcn_mfma_f32_16x16x32_bf16(
                        b[fn], a[ks][fm], acc[fm][fn], 0, 0, 0);   // SWAPPED
        }

        const bool gate = (cc == 3);
        unsigned short* ob = (cc == 3) ? gb : (unsigned short*)0;
        unsigned char*  f8 = (cc == 0) ? qf8 : (cc == 1) ? kf8 : (cc == 2) ? vf8 : (unsigned char*)0;

        #pragma unroll
        for (int fm = 0; fm < 4; ++fm) {
            const int row = row0 + wm*64 + fm*16 + l15;
            #pragma unroll
            for (int fn = 0; fn < 4; ++fn) {
                const int cbase = wn*64 + fn*16 + lg*4;
                float v0 = acc[fm][fn][0], v1 = acc[fm][fn][1];
                float v2 = acc[fm][fn][2], v3 = acc[fm][fn][3];
                if (gate) {
                    const float4 bg4 = *(const float4*)(bg + cbase);
                    v0 = 1.f/(1.f + __expf(-(v0 + bg4.x)));
                    v1 = 1.f/(1.f + __expf(-(v1 + bg4.y)));
                    v2 = 1.f/(1.f + __expf(-(v2 + bg4.z)));
                    v3 = 1.f/(1.f + __expf(-(v3 + bg4.w)));
                    uint2 o;
                    o.x = pack2(v0, v1);
                    o.y = pack2(v2, v3);
                    *(uint2*)(ob + (size_t)row * IFZ + cbase) = o;
                } else {
                    int p = __builtin_amdgcn_cvt_pk_fp8_f32(v0, v1, 0, false);
                    p     = __builtin_amdgcn_cvt_pk_fp8_f32(v2, v3, p, true);
                    *(unsigned*)(f8 + (size_t)row*128 + cbase) = (unsigned)p;
                }
            }
        }
    }
}

// ---------------------------------------------------------------------------
// attn_back_ln v6: q/k self-rows staged as fp8 (LDS halved, ~22 KB);
// phase-1 dots via cvt_pk_f32_fp8; phase 3 EXACT R13 structure (2-byte V
// loads, full unroll, max MLP). ctxb aliases the staging region.
// ---------------------------------------------------------------------------
__global__ __launch_bounds__(256) void attn_back_ln(
    const unsigned short* __restrict__ gb,
    const float* __restrict__ bbuf, const int* __restrict__ edge,
    const unsigned char* __restrict__ qf8, const unsigned char* __restrict__ kf8,
    const unsigned char* __restrict__ vf8,
    const float* __restrict__ x, const unsigned short* __restrict__ Wbt,
    const float* __restrict__ bback, const float* __restrict__ gamma,
    const float* __restrict__ beta, float* __restrict__ out)
{
    const int n   = blockIdx.x;
    const int tid = threadIdx.x;

    __shared__ unsigned smemA[2176];     // qsu8[0..719] | ksu8[720..1439]; ctxb aliases (2176)
    __shared__ float    scys[3280];      // scores, then ys (aliased)
    __shared__ float    bs[KZ*AHZ];
    __shared__ float    st2[KZ][2];
    __shared__ int      es[KZ];

    unsigned* qsu8 = smemA;              // [kk][a][8] fp8 uints, kk stride 36
    unsigned* ksu8 = smemA + 720;
    unsigned* ctxb = smemA;              // 32*68 uints; valid from phase 3 on

    const size_t base  = (size_t)n * (KZ*IFZ);
    const size_t base2 = base >> 1;              // uint index

    {
        const uint4* qsrc = (const uint4*)(qf8 + (size_t)n*(KZ*128));
        const uint4* ksrc = (const uint4*)(kf8 + (size_t)n*(KZ*128));
        for (int i = tid; i < KZ*8; i += 256) {
            const int r = i >> 3, u8 = i & 7;
            const int d = r*36 + (u8 >> 1)*8 + (u8 & 1)*4;
            *(uint4*)&qsu8[d] = qsrc[i];
            *(uint4*)&ksu8[d] = ksrc[i];
        }
    }
    if (tid < KZ)      es[tid] = edge[n*KZ + tid];
    if (tid < KZ*AHZ)  bs[tid] = bbuf[(size_t)n*(KZ*AHZ) + tid];
    __syncthreads();

    const float rscale = 0.17677669529663687f;  // 1/sqrt(32)

    // ---- Phase 1a: self scores, it-loop, fp8 both sides (1600 items).
    for (int it = tid; it < KZ*KZ*AHZ; it += 256) {
        const int a  = it & 3;
        const int j  = (it >> 2) % KZ;
        const int kk = it / (KZ*AHZ);
        const unsigned* qrow = &qsu8[kk*36 + a*8];
        const unsigned* krow = &ksu8[j*36 + a*8];
        const uint4 q0 = *(const uint4*)&qrow[0];
        const uint4 q1 = *(const uint4*)&qrow[4];
        const uint4 k0 = *(const uint4*)&krow[0];
        const uint4 k1 = *(const uint4*)&krow[4];
        const float s = dotf8_16(q0, k0) + dotf8_16(q1, k1);
        scys[(kk*4 + a)*41 + j] = s*rscale + bs[j*AHZ + a];
    }

    // ---- Phase 1b: neighbor scores, fp8 q (LDS) x fp8 k (gather) (1600 items).
    for (int it = tid; it < KZ*KZ*AHZ; it += 256) {
        const int a  = it & 3;
        const int jj = (it >> 2) % KZ;
        const int kk = it / (KZ*AHZ);
        const int e  = es[kk];
        const unsigned* qrow = &qsu8[kk*36 + a*8];
        const uint4 q0 = *(const uint4*)&qrow[0];
        const uint4 q1 = *(const uint4*)&qrow[4];
        const unsigned char* kp = kf8 + ((size_t)e*KZ + jj)*128 + a*32;
        const uint4 k0 = *(const uint4*)kp;
        const uint4 k1 = *(const uint4*)(kp + 16);
        const float s = dotf8_16(q0, k0) + dotf8_16(q1, k1);
        scys[(kk*4 + a)*41 + KZ + jj] = s*rscale + bbuf[((size_t)e*KZ + jj)*AHZ + a];
    }
    __syncthreads();

    // ---- Phase 2: softmax over 40 keys, one thread per (kk,a) row.
    if (tid < KZ*AHZ) {
        float* row = &scys[tid*41];
        float m = row[0];
        #pragma unroll
        for (int j = 1; j < TWO_KZ; ++j) m = fmaxf(m, row[j]);
        float ssum = 0.f;
        #pragma unroll
        for (int j = 0; j < TWO_KZ; ++j) { const float e = __expf(row[j]-m); row[j] = e; ssum += e; }
        const float inv = 1.f/ssum;
        #pragma unroll
        for (int j = 0; j < TWO_KZ; ++j) row[j] *= inv;
    }
    __syncthreads();     // qsu8/ksu8/bs now dead -> ctxb may overwrite

    // ---- Phase 3 (R13-exact): ctx + gate -> ctxb. it = kk*64 + c2, 2B loads,
    // full unroll -> 40 outstanding tiny loads/thread = max MLP.
    {
        for (int i = tid; i < 12*68; i += 256) ctxb[20*68 + i] = 0u;

        const unsigned* gbu = (const unsigned*)gb;
        for (int it = tid; it < KZ*64; it += 256) {
            const int kk = it >> 6;
            const int c2 = it & 63;
            const int a  = c2 >> 4;
            const float* wrow = &scys[(kk*4 + a)*41];
            float acc0 = 0.f, acc1 = 0.f;
            const unsigned char* vself = vf8 + (size_t)n*(KZ*128) + c2*2;
            #pragma unroll
            for (int j = 0; j < KZ; ++j) {
                const unsigned u = *(const unsigned short*)(vself + j*128);
                const f32x2 v2 = __builtin_amdgcn_cvt_pk_f32_fp8(u, false);
                const float w = wrow[j];
                acc0 += w*v2.x; acc1 += w*v2.y;
            }
            const unsigned char* vnb = vf8 + (size_t)es[kk]*(KZ*128) + c2*2;
            #pragma unroll
            for (int j = 0; j < KZ; ++j) {
                const unsigned u = *(const unsigned short*)(vnb + j*128);
                const f32x2 v2 = __builtin_amdgcn_cvt_pk_f32_fp8(u, false);
                const float w = wrow[KZ + j];
                acc0 += w*v2.x; acc1 += w*v2.y;
            }
            const unsigned gu = gbu[base2 + it];
            ctxb[kk*68 + c2] = pack2(acc0 * blo(gu), acc1 * bhi(gu));
        }
    }
    __syncthreads();     // ctxb ready; scys (scores) dead -> becomes ys

    // ---- Phase 4: back-GEMM compute (MFMA) + ys init (overlapped).
    const int wid  = tid >> 6;
    const int lane = tid & 63;
    const int l15  = lane & 15, lg = lane >> 4;
    const float SQ2 = 1.4142135623730951f;

    f32x4 bacc[2][2];
    #pragma unroll
    for (int i = 0; i < 2; ++i)
        #pragma unroll
        for (int j = 0; j < 2; ++j) bacc[i][j] = (f32x4){0.f,0.f,0.f,0.f};

    #pragma unroll
    for (int ks = 0; ks < 4; ++ks) {
        short8v bfr[2], afr[2];
        #pragma unroll
        for (int fn = 0; fn < 2; ++fn)
            bfr[fn] = *((const short8v*)(Wbt + (size_t)(wid*32 + fn*16 + l15)*IFZ + ks*32 + lg*8));
        #pragma unroll
        for (int fm = 0; fm < 2; ++fm)
            afr[fm] = *((const short8v*)&ctxb[(fm*16 + l15)*68 + ks*16 + lg*4]);
        #pragma unroll
        for (int fm = 0; fm < 2; ++fm)
            #pragma unroll
            for (int fn = 0; fn < 2; ++fn)
                bacc[fm][fn] = __builtin_amdgcn_mfma_f32_16x16x32_bf16(
                    bfr[fn], afr[fm], bacc[fm][fn], 0, 0, 0);   // SWAPPED
    }

    // ys init: ys[r][c] = sqrt2*x + bback (640 float4 items over 256 threads)
    for (int i = tid; i < 640; i += 256) {
        const int r = i >> 5, c4 = (i & 31) * 4;
        const float4 xv  = *(const float4*)(x + base + (size_t)r*IFZ + c4);
        const float4 bb4 = *(const float4*)(bback + c4);
        float* yp = &scys[r*132 + c4];
        yp[0] = SQ2*xv.x + bb4.x; yp[1] = SQ2*xv.y + bb4.y;
        yp[2] = SQ2*xv.z + bb4.z; yp[3] = SQ2*xv.w + bb4.w;
    }
    __syncthreads();

    // ---- Phase 5: add fragments into ys (unique (row,col) ownership).
    #pragma unroll
    for (int fm = 0; fm < 2; ++fm) {
        const int row = fm*16 + l15;
        if (row < KZ) {
            #pragma unroll
            for (int fn = 0; fn < 2; ++fn) {
                const int cb = wid*32 + fn*16 + lg*4;
                float* yp = &scys[row*132 + cb];
                yp[0] += bacc[fm][fn][0]; yp[1] += bacc[fm][fn][1];
                yp[2] += bacc[fm][fn][2]; yp[3] += bacc[fm][fn][3];
            }
        }
    }
    __syncthreads();

    // ---- Phase 6: LN stats, 8 threads per row (20 rows x 8 = 160).
    if (tid < 160) {
        const int row = tid >> 3, t = tid & 7;
        float s1 = 0.f, s2 = 0.f;
        #pragma unroll
        for (int i = 0; i < 16; ++i) {
            const float v = scys[row*132 + t*16 + i];
            s1 += v; s2 += v*v;
        }
        s1 += __shfl_xor(s1, 1); s2 += __shfl_xor(s2, 1);
        s1 += __shfl_xor(s1, 2); s2 += __shfl_xor(s2, 2);
        s1 += __shfl_xor(s1, 4); s2 += __shfl_xor(s2, 4);
        if (t == 0) {
            const float mean = s1 * (1.f/IFZ);
            const float var  = s2 * (1.f/IFZ) - mean*mean;
            st2[row][0] = mean;
            st2[row][1] = rsqrtf(var + 1e-5f);
        }
    }
    __syncthreads();

    // ---- Phase 7: normalize + write f32 out.
    for (int i = tid; i < 640; i += 256) {
        const int r = i >> 5, c4 = (i & 31) * 4;
        const float mean = st2[r][0], rstd = st2[r][1];
        const float4 g4 = *(const float4*)(gamma + c4);
        const float4 b4 = *(const float4*)(beta + c4);
        const float4 yv = *(const float4*)&scys[r*132 + c4];
        float4 o;
        o.x = g4.x*(yv.x - mean)*rstd + b4.x;
        o.y = g4.y*(yv.y - mean)*rstd + b4.y;
        o.z = g4.z*(yv.z - mean)*rstd + b4.z;
        o.w = g4.w*(yv.w - mean)*rstd + b4.w;
        *(float4*)(out + base + (size_t)r*IFZ + c4) = o;
    }
}

// ---------------------------------------------------------------------------
extern "C" void kernel_launch(void* const* d_in, const int* in_sizes, int n_in,
                              void* d_out, int out_size, void* d_ws, size_t ws_size,
                              hipStream_t stream) {
    const float* x     = (const float*)d_in[0];
    const int*   edge  = (const int*)  d_in[1];
    const float* Wq    = (const float*)d_in[2];
    const float* Wk    = (const float*)d_in[3];
    const float* Wv    = (const float*)d_in[4];
    const float* Wb    = (const float*)d_in[5];
    const float* Wg    = (const float*)d_in[6];
    const float* bg    = (const float*)d_in[7];
    const float* Wback = (const float*)d_in[8];
    const float* bback = (const float*)d_in[9];
    const float* gamma = (const float*)d_in[10];
    const float* beta  = (const float*)d_in[11];
    float* out = (float*)d_out;

    const size_t RE = (size_t)ROWS * IFZ;   // 5,242,880 elements
    unsigned short* gb  = (unsigned short*)d_ws;     // RE ushorts
    unsigned short* Wt  = gb + RE;          // 512*128
    unsigned short* Wbt = Wt + 512*128;     // 128*128
    float*          bbuf= (float*)(Wbt + 128*128);   // ROWS*4 f32
    unsigned char*  qf8 = (unsigned char*)(bbuf + (size_t)ROWS*4);  // ROWS*128 B
    unsigned char*  kf8 = qf8 + RE;                                  // ROWS*128 B
    unsigned char*  vf8 = kf8 + RE;                                  // ROWS*128 B
    // total ws use ~27 MB

    setup_kernel<<<480, 256, 0, stream>>>(x, Wq, Wk, Wv, Wg, Wback, Wb,
                                          Wt, Wbt, bbuf);
    proj_gemm  <<<ROWS/128, 256, 0, stream>>>(x, Wt, bg, gb, qf8, kf8, vf8);
    attn_back_ln<<<NN, 256, 0, stream>>>(gb, bbuf, edge, qf8, kf8, vf8,
                                         x, Wbt, bback, gamma, beta, out);
}